// Round 7
// baseline (37.463 us; speedup 1.0000x reference)
//
#include <hip/hip_runtime.h>

#define BB 4
#define SS 4096
#define EE 128

typedef __attribute__((ext_vector_type(8))) short bf16x8;
typedef __attribute__((ext_vector_type(4))) float f32x4;

__device__ __forceinline__ unsigned short f2bf(float f) {
    unsigned u = __float_as_uint(f);
    u = (u + 0x7FFFu + ((u >> 16) & 1u)) >> 16;
    return (unsigned short)u;
}
__device__ __forceinline__ float bf2f(unsigned short h) {
    return __uint_as_float(((unsigned)h) << 16);
}
__device__ __forceinline__ void split8(const float* p, bf16x8& h, bf16x8& l) {
    float4 v0 = *reinterpret_cast<const float4*>(p);
    float4 v1 = *reinterpret_cast<const float4*>(p + 4);
    float f[8] = {v0.x, v0.y, v0.z, v0.w, v1.x, v1.y, v1.z, v1.w};
    #pragma unroll
    for (int i = 0; i < 8; ++i) {
        unsigned short hb = f2bf(f[i]);
        h[i] = (short)hb;
        l[i] = (short)f2bf(f[i] - bf2f(hb));
    }
}
// 3-product split-bf16 MFMA: a*b at ~f32 accuracy (drops lo*lo, ~2^-18 rel)
__device__ __forceinline__ f32x4 mfma3(bf16x8 ah, bf16x8 al, bf16x8 bh, bf16x8 bl, f32x4 c) {
    c = __builtin_amdgcn_mfma_f32_16x16x32_bf16(ah, bh, c, 0, 0, 0);
    c = __builtin_amdgcn_mfma_f32_16x16x32_bf16(al, bh, c, 0, 0, 0);
    c = __builtin_amdgcn_mfma_f32_16x16x32_bf16(ah, bl, c, 0, 0, 0);
    return c;
}

// ---------------------------------------------------------------------------
// prep: blocks [0,256): b=bx>>6, i=bx&63: chunk = x[b, 64+i*63 .. +63, :]
//       vpart[b][i][c] = (column sums of chunk) . Wv[c]   (f32)
//       blocks [256,260): b = bx-256, ONE block per batch, 4 waves, all MFMA:
//         wave w owns t-strip [16w,16w+16):
//         K:  ksub[t][j] = (t<=j) ? x64[t].Wk[j] : 0       (split-MFMA, ->LDS)
//         Mt: Mt[t][e]   = sum_j ksub[t][j]*Wq[j][e]       (split-MFMA, bf16 hi/lo)
//         V:  Vt[v][t]   = bf16( x64[t].Wv[v] )            (split-MFMA, transposed)
// ---------------------------------------------------------------------------
__global__ __launch_bounds__(256, 2)
void prep(const float* __restrict__ x, const float* __restrict__ Wk,
          const float* __restrict__ Wq, const float* __restrict__ Wv,
          unsigned short* __restrict__ Vt,
          unsigned short* __restrict__ Mth, unsigned short* __restrict__ Mtl,
          float* __restrict__ vpart)
{
    __shared__ unsigned short wqTh[128][72];   // [e][j] pre-split bf16 hi
    __shared__ unsigned short wqTl[128][72];   // [e][j] pre-split bf16 lo
    __shared__ float ksub[64][68];             // masked K [t][j] f32
    const int tid = threadIdx.x;
    const int bx = blockIdx.x;

    if (bx < 256) {
        // ---- xpart chunk sum + Wv projection (overlay ksub) ----
        float* w = &ksub[0][0];          // [0:128)=rg0, [128:256)=rg1, [256:384)=xsum
        const int b = bx >> 6, i = bx & 63;
        const size_t base = ((size_t)b * SS + 64 + (size_t)i * 63) * EE;
        const int col = tid & 127, rg = tid >> 7;
        float s = 0.f;
        for (int r = rg; r < 63; r += 2)
            s += x[base + (size_t)r * EE + col];
        w[rg * 128 + col] = s;
        __syncthreads();
        if (tid < 128) w[256 + tid] = w[tid] + w[128 + tid];
        __syncthreads();
        if (tid < 128) {
            float a = 0.f;
            #pragma unroll 8
            for (int e = 0; e < 128; e += 4) {
                float4 wv = *reinterpret_cast<const float4*>(Wv + (size_t)tid * EE + e);
                a = fmaf(w[256 + e + 0], wv.x, a);
                a = fmaf(w[256 + e + 1], wv.y, a);
                a = fmaf(w[256 + e + 2], wv.z, a);
                a = fmaf(w[256 + e + 3], wv.w, a);
            }
            vpart[((size_t)b * 64 + i) * 128 + tid] = a;
        }
        return;
    }

    // ================= special block: one per batch, all-MFMA =================
    const int b = bx - 256;
    const int l = tid & 63, wv_ = tid >> 6;        // wave id
    const int lm = l & 15, lg = l >> 4;
    const int t0 = wv_ * 16;                       // this wave's t-strip

    // ---- stage Wq^T pre-split: wqT[e][j] from Wq[j][e] (64x128 f32) ----
    #pragma unroll
    for (int i = 0; i < 8; ++i) {
        int f4 = tid + i * 256;                    // 2048 float4 total
        int j = f4 >> 5, eq = f4 & 31;
        float4 v = *reinterpret_cast<const float4*>(Wq + (size_t)j * EE + 4 * eq);
        float vf[4] = {v.x, v.y, v.z, v.w};
        #pragma unroll
        for (int c = 0; c < 4; ++c) {
            unsigned short hb = f2bf(vf[c]);
            wqTh[4 * eq + c][j] = hb;
            wqTl[4 * eq + c][j] = f2bf(vf[c] - bf2f(hb));
        }
    }

    // ---- x64 A-frags for this strip (reused by K and V GEMMs) ----
    bf16x8 xh[4], xl[4];
    const float* xrow = x + ((size_t)b * SS + t0 + lm) * EE + lg * 8;
    #pragma unroll
    for (int kt = 0; kt < 4; ++kt)
        split8(xrow + kt * 32, xh[kt], xl[kt]);

    // ---- K-GEMM: K[t][j] = x64[t].Wk[j]; mask; -> ksub (own rows only) ----
    #pragma unroll
    for (int jt = 0; jt < 4; ++jt) {
        f32x4 a = {0.f, 0.f, 0.f, 0.f};
        const float* wkr = Wk + (size_t)(jt * 16 + lm) * EE + lg * 8;
        #pragma unroll
        for (int kt = 0; kt < 4; ++kt) {
            bf16x8 bh, bl;
            split8(wkr + kt * 32, bh, bl);
            a = mfma3(xh[kt], xl[kt], bh, bl, a);
        }
        const int j = jt * 16 + lm;
        #pragma unroll
        for (int r = 0; r < 4; ++r) {
            const int t = t0 + lg * 4 + r;
            ksub[t][j] = (t <= j) ? a[r] : 0.f;
        }
    }
    __syncthreads();                               // wqT visible (ksub is same-wave)

    // ---- Mt-GEMM: Mt[t][e] = sum_j ksub[t][j] * Wq[j][e] ----
    bf16x8 kh[2], kl[2];
    #pragma unroll
    for (int kt2 = 0; kt2 < 2; ++kt2)
        split8(&ksub[t0 + lm][kt2 * 32 + lg * 8], kh[kt2], kl[kt2]);
    #pragma unroll
    for (int et = 0; et < 8; ++et) {
        f32x4 a = {0.f, 0.f, 0.f, 0.f};
        #pragma unroll
        for (int kt2 = 0; kt2 < 2; ++kt2) {
            const int e = et * 16 + lm, j0 = kt2 * 32 + lg * 8;
            bf16x8 qh = *reinterpret_cast<const bf16x8*>(&wqTh[e][j0]);
            bf16x8 ql = *reinterpret_cast<const bf16x8*>(&wqTl[e][j0]);
            a = mfma3(kh[kt2], kl[kt2], qh, ql, a);
        }
        #pragma unroll
        for (int r = 0; r < 4; ++r) {
            const int t = t0 + lg * 4 + r, e = et * 16 + lm;
            const size_t off = (size_t)b * 8192 + (size_t)t * 128 + e;
            unsigned short hb = f2bf(a[r]);
            Mth[off] = hb;
            Mtl[off] = f2bf(a[r] - bf2f(hb));
        }
    }

    // ---- V-GEMM: V[t][v] = x64[t].Wv[v]; store Vt[v][t] bf16 ----
    #pragma unroll
    for (int vt = 0; vt < 8; ++vt) {
        f32x4 a = {0.f, 0.f, 0.f, 0.f};
        const float* wvr = Wv + (size_t)(vt * 16 + lm) * EE + lg * 8;
        #pragma unroll
        for (int kt = 0; kt < 4; ++kt) {
            bf16x8 bh, bl;
            split8(wvr + kt * 32, bh, bl);
            a = mfma3(xh[kt], xl[kt], bh, bl, a);
        }
        const int v = vt * 16 + lm;
        #pragma unroll
        for (int r = 0; r < 4; ++r) {
            const int t = t0 + lg * 4 + r;
            Vt[(size_t)b * 8192 + (size_t)v * 64 + t] = f2bf(a[r]);
        }
    }
}

// ---------------------------------------------------------------------------
// main: 1 wave per block, 16 q-rows. vsum prologue (64 fixed-order vpart
// partials), S = x@M via split-bf16 MFMA, in-register softmax (+4032
// zero-col term), P relayout via LDS, out = (P@V + e*vsum) * iz.
// ---------------------------------------------------------------------------
__global__ __launch_bounds__(64)
void attn_main(const float* __restrict__ x, const short* __restrict__ Mth,
               const short* __restrict__ Mtl, const short* __restrict__ Vt,
               const float* __restrict__ vpart, float* __restrict__ out)
{
    __shared__ float Plds[16][68];
    __shared__ float vsS[128];
    const int l = threadIdx.x;
    const int b = blockIdx.y;
    const int s0 = blockIdx.x * 16;
    const int lm = l & 15, lg = l >> 4;

    // ---- vsum reduction: lane owns cols (2l, 2l+1); needed only at the end ----
    float2 vac = make_float2(0.f, 0.f);
    {
        const float* vp = vpart + (size_t)b * 8192 + 2 * l;
        #pragma unroll 8
        for (int i = 0; i < 64; ++i) {
            float2 t = *reinterpret_cast<const float2*>(vp + (size_t)i * 128);
            vac.x += t.x; vac.y += t.y;
        }
    }
    *reinterpret_cast<float2*>(&vsS[2 * l]) = vac;

    // ---- x A-frags (hi/lo split) ----
    bf16x8 xh[4], xl[4];
    const float* xrow = x + ((size_t)b * SS + s0 + lm) * EE + lg * 8;
    #pragma unroll
    for (int kt = 0; kt < 4; ++kt)
        split8(xrow + kt * 32, xh[kt], xl[kt]);

    // ---- S = x @ M : 4 col-tiles x (4 k-tiles x 3 split-mfma) ----
    f32x4 sa[4];
    const short* mh_base = Mth + (size_t)b * 8192 + lg * 8;
    const short* ml_base = Mtl + (size_t)b * 8192 + lg * 8;
    #pragma unroll
    for (int ct = 0; ct < 4; ++ct) {
        f32x4 a = {0.f, 0.f, 0.f, 0.f};
        const size_t trow = (size_t)(ct * 16 + lm) * 128;
        #pragma unroll
        for (int kt = 0; kt < 4; ++kt) {
            bf16x8 mh = *reinterpret_cast<const bf16x8*>(mh_base + trow + kt * 32);
            bf16x8 ml = *reinterpret_cast<const bf16x8*>(ml_base + trow + kt * 32);
            a = __builtin_amdgcn_mfma_f32_16x16x32_bf16(xh[kt], mh, a, 0, 0, 0);
            a = __builtin_amdgcn_mfma_f32_16x16x32_bf16(xl[kt], mh, a, 0, 0, 0);
            a = __builtin_amdgcn_mfma_f32_16x16x32_bf16(xh[kt], ml, a, 0, 0, 0);
        }
        sa[ct] = a;
    }

    // ---- softmax over 4096 cols (64 real + 4032 exact zeros) ----
    float e[4], iz[4];
    #pragma unroll
    for (int r = 0; r < 4; ++r) {
        float m = fmaxf(fmaxf(sa[0][r], sa[1][r]), fmaxf(sa[2][r], sa[3][r]));
        #pragma unroll
        for (int o = 1; o < 16; o <<= 1) m = fmaxf(m, __shfl_xor(m, o));
        m = fmaxf(m, 0.f);
        float w0 = __expf(sa[0][r] - m), w1 = __expf(sa[1][r] - m);
        float w2 = __expf(sa[2][r] - m), w3 = __expf(sa[3][r] - m);
        sa[0][r] = w0; sa[1][r] = w1; sa[2][r] = w2; sa[3][r] = w3;
        float z = (w0 + w1) + (w2 + w3);
        #pragma unroll
        for (int o = 1; o < 16; o <<= 1) z += __shfl_xor(z, o);
        e[r] = __expf(-m);
        z += 4032.f * e[r];
        iz[r] = 1.f / z;
    }

    // ---- P relayout: C/D layout -> A-frag layout via LDS ----
    #pragma unroll
    for (int ct = 0; ct < 4; ++ct)
        #pragma unroll
        for (int r = 0; r < 4; ++r)
            Plds[lg * 4 + r][ct * 16 + lm] = sa[ct][r];
    bf16x8 pf[2];
    #pragma unroll
    for (int kt2 = 0; kt2 < 2; ++kt2) {
        const float* pr = &Plds[lm][kt2 * 32 + lg * 8];
        #pragma unroll
        for (int i = 0; i < 8; ++i) pf[kt2][i] = (short)f2bf(pr[i]);
    }

    // ---- PV + vsum term + normalize + store ----
    const short* vb = Vt + (size_t)b * 8192 + lg * 8;
    const size_t obase = ((size_t)b * SS + s0) * EE;
    #pragma unroll
    for (int ct = 0; ct < 8; ++ct) {
        const int col = ct * 16 + lm;
        bf16x8 v0 = *reinterpret_cast<const bf16x8*>(vb + (size_t)col * 64);
        bf16x8 v1 = *reinterpret_cast<const bf16x8*>(vb + (size_t)col * 64 + 32);
        f32x4 a = {0.f, 0.f, 0.f, 0.f};
        a = __builtin_amdgcn_mfma_f32_16x16x32_bf16(pf[0], v0, a, 0, 0, 0);
        a = __builtin_amdgcn_mfma_f32_16x16x32_bf16(pf[1], v1, a, 0, 0, 0);
        const float vs = vsS[col];
        #pragma unroll
        for (int r = 0; r < 4; ++r)
            out[obase + (size_t)(lg * 4 + r) * EE + col] = (a[r] + e[r] * vs) * iz[r];
    }
}

// ---------------------------------------------------------------------------
extern "C" void kernel_launch(void* const* d_in, const int* in_sizes, int n_in,
                              void* d_out, int out_size, void* d_ws, size_t ws_size,
                              hipStream_t stream)
{
    const float* x  = (const float*)d_in[0];
    const float* Wk = (const float*)d_in[1];
    const float* Wq = (const float*)d_in[2];
    const float* Wv = (const float*)d_in[3];
    float* out = (float*)d_out;

    float* ws = (float*)d_ws;
    float* vpart = ws;                                     // 4*64*128 f32
    unsigned short* Mth = (unsigned short*)(vpart + 32768);// 4*64*128 bf16
    unsigned short* Mtl = Mth + 32768;                     // 4*64*128 bf16
    unsigned short* Vt  = Mtl + 32768;                     // 4*128*64 bf16

    prep<<<260, 256, 0, stream>>>(x, Wk, Wq, Wv, Vt, Mth, Mtl, vpart);
    attn_main<<<dim3(SS / 16, BB), 64, 0, stream>>>(
        x, (const short*)Mth, (const short*)Mtl, (const short*)Vt, vpart, out);
}